// Round 1
// baseline (1161.463 us; speedup 1.0000x reference)
//
#include <hip/hip_runtime.h>
#include <cfloat>

#define W 512
#define H 512
#define B 4
#define HW (W*H)
#define NTOT (B*HW)
#define CFEAT 128
#define K 512
#define NBINS 65536
#define CAP 49152   // >= theoretical max NMS maxima per batch (3 * (512/4)^2)

// ---------------- init ----------------
__global__ void zero_ws_k(unsigned* __restrict__ hist, int* __restrict__ count) {
    int i = blockIdx.x * blockDim.x + threadIdx.x;
    if (i < B * NBINS) hist[i] = 0u;
    if (i < B) count[i] = 0;
}

// ---------------- score2d = raw * (bev[:,2] > 0) ----------------
__global__ void score_k(const float* __restrict__ bev, const float* __restrict__ raw,
                        float* __restrict__ scores) {
    int i = blockIdx.x * blockDim.x + threadIdx.x;
    if (i >= NTOT) return;
    int b = i >> 18;
    int hw = i & (HW - 1);
    float g = bev[(b * 7 + 2) * HW + hw] > 0.f ? 1.f : 0.f;
    scores[i] = raw[i] * g;
}

// ---------------- horizontal 7-tap max ----------------
__global__ void hmax_k(const float* __restrict__ in, float* __restrict__ out) {
    int i = blockIdx.x * blockDim.x + threadIdx.x;
    if (i >= NTOT) return;
    int v = i & (W - 1);
    float m = in[i];
#pragma unroll
    for (int d = 1; d <= 3; ++d) {
        if (v - d >= 0) m = fmaxf(m, in[i - d]);
        if (v + d < W)  m = fmaxf(m, in[i + d]);
    }
    out[i] = m;
}

// horizontal 7-tap max of suppressed scores (supp ? 0 : scores), on the fly
__global__ void hmax_supp_k(const float* __restrict__ scores, const float* __restrict__ supp,
                            float* __restrict__ out) {
    int i = blockIdx.x * blockDim.x + threadIdx.x;
    if (i >= NTOT) return;
    int v = i & (W - 1);
    float m = supp[i] > 0.f ? 0.f : scores[i];
#pragma unroll
    for (int d = 1; d <= 3; ++d) {
        if (v - d >= 0) { int j = i - d; m = fmaxf(m, supp[j] > 0.f ? 0.f : scores[j]); }
        if (v + d < W)  { int j = i + d; m = fmaxf(m, supp[j] > 0.f ? 0.f : scores[j]); }
    }
    out[i] = m;
}

// ---------------- vertical 7-tap max, fused consumers ----------------
__global__ void vmax_eq_k(const float* __restrict__ tmp, const float* __restrict__ scores,
                          float* __restrict__ mask) {
    int i = blockIdx.x * blockDim.x + threadIdx.x;
    if (i >= NTOT) return;
    int h = (i >> 9) & (H - 1);
    float m = tmp[i];
#pragma unroll
    for (int d = 1; d <= 3; ++d) {
        if (h - d >= 0) m = fmaxf(m, tmp[i - (d << 9)]);
        if (h + d < H)  m = fmaxf(m, tmp[i + (d << 9)]);
    }
    mask[i] = (scores[i] == m) ? 1.f : 0.f;
}

__global__ void vmax_supp_k(const float* __restrict__ tmp, float* __restrict__ supp) {
    int i = blockIdx.x * blockDim.x + threadIdx.x;
    if (i >= NTOT) return;
    int h = (i >> 9) & (H - 1);
    float m = tmp[i];
#pragma unroll
    for (int d = 1; d <= 3; ++d) {
        if (h - d >= 0) m = fmaxf(m, tmp[i - (d << 9)]);
        if (h + d < H)  m = fmaxf(m, tmp[i + (d << 9)]);
    }
    supp[i] = m > 0.f ? 1.f : 0.f;
}

// new_max = (supp_scores == vmax(tmp)) & !supp ; mask |= new_max
__global__ void vmax_new_k(const float* __restrict__ tmp, const float* __restrict__ scores,
                           const float* __restrict__ supp, float* __restrict__ mask) {
    int i = blockIdx.x * blockDim.x + threadIdx.x;
    if (i >= NTOT) return;
    int h = (i >> 9) & (H - 1);
    float m = tmp[i];
#pragma unroll
    for (int d = 1; d <= 3; ++d) {
        if (h - d >= 0) m = fmaxf(m, tmp[i - (d << 9)]);
        if (h + d < H)  m = fmaxf(m, tmp[i + (d << 9)]);
    }
    float sup = supp[i];
    float ss = sup > 0.f ? 0.f : scores[i];
    bool newm = (ss == m) && (sup == 0.f);
    mask[i] = ((mask[i] > 0.f) || newm) ? 1.f : 0.f;
}

// ---------------- compact candidates + histogram ----------------
__global__ void compact_k(const float* __restrict__ scores, const float* __restrict__ mask,
                          float* __restrict__ cval, int* __restrict__ cidx,
                          int* __restrict__ count, unsigned* __restrict__ hist) {
    int i = blockIdx.x * blockDim.x + threadIdx.x;
    if (i >= NTOT) return;
    if (mask[i] > 0.f) {
        float v = scores[i];
        if (v > 0.f) {
            int b = i >> 18;
            int p = atomicAdd(&count[b], 1);
            if (p < CAP) { cval[b * CAP + p] = v; cidx[b * CAP + p] = i & (HW - 1); }
            unsigned bin = (unsigned)(v * 65536.f);
            if (bin > 65535u) bin = 65535u;
            atomicAdd(&hist[b * NBINS + bin], 1u);
        }
    }
}

// ---------------- per-batch exact top-K (value desc, idx asc) ----------------
__global__ __launch_bounds__(512) void select_k(
    const float* __restrict__ cval, const int* __restrict__ cidx,
    const int* __restrict__ count, const unsigned* __restrict__ hist,
    const float* __restrict__ scores, const float* __restrict__ mask,
    const float* __restrict__ bev,
    float* __restrict__ out_kpts, float* __restrict__ out_pix, int* __restrict__ topk_idx) {
    __shared__ float sval[1024];
    __shared__ int   sidx[1024];
    __shared__ unsigned part[512];
    __shared__ int final_idx[K];
    __shared__ int nsel_s, tbin_s;

    int b = blockIdx.x, t = threadIdx.x;
    int total = count[b];
    if (total > CAP) total = CAP;
    const unsigned* Hh = hist + b * NBINS;

    // per-thread partial sums over 128 bins each
    unsigned s = 0;
    const int SPAN = NBINS / 512;
#pragma unroll 4
    for (int i = 0; i < SPAN; ++i) s += Hh[t * SPAN + i];
    part[t] = s;
    if (t == 0) nsel_s = 0;
    __syncthreads();

    if (t == 0) {
        if (total <= K) {
            tbin_s = 0;
        } else {
            unsigned acc = 0; int seg = 0; unsigned before = 0;
            for (int sg = 511; sg >= 0; --sg) {
                if (acc + part[sg] >= (unsigned)K) { seg = sg; before = acc; break; }
                acc += part[sg];
            }
            int base = seg * SPAN;
            unsigned a2 = before; int T = base;
            for (int bin = base + SPAN - 1; bin >= base; --bin) {
                a2 += Hh[bin];
                if (a2 >= (unsigned)K) { T = bin; break; }
            }
            tbin_s = T;
        }
    }
    __syncthreads();
    int tb = tbin_s;

    // collect superset (all candidates with bin >= threshold bin)
    for (int i = t; i < total; i += 512) {
        float v = cval[b * CAP + i];
        unsigned bin = (unsigned)(v * 65536.f);
        if (bin > 65535u) bin = 65535u;
        if ((int)bin >= tb) {
            int p = atomicAdd(&nsel_s, 1);
            if (p < 1024) { sval[p] = v; sidx[p] = cidx[b * CAP + i]; }
        }
    }
    __syncthreads();
    int ns = nsel_s < 1024 ? nsel_s : 1024;
    for (int i = t; i < 1024; i += 512)
        if (i >= ns) { sval[i] = -FLT_MAX; sidx[i] = 0x40000000 + i; }
    __syncthreads();

    // bitonic sort, final order: value desc, ties idx asc
    for (int kk = 2; kk <= 1024; kk <<= 1) {
        for (int j = kk >> 1; j > 0; j >>= 1) {
            for (int idx = t; idx < 1024; idx += 512) {
                int p = idx ^ j;
                if (p > idx) {
                    float va = sval[idx], vb = sval[p];
                    int ia = sidx[idx], ib = sidx[p];
                    bool up = ((idx & kk) == 0);
                    bool b_first = (vb > va) || (vb == va && ib < ia);
                    if (b_first == up) {
                        sval[idx] = vb; sval[p] = va;
                        sidx[idx] = ib; sidx[p] = ia;
                    }
                }
            }
            __syncthreads();
        }
    }

    int valid = total < K ? total : K;
    if (t < valid) final_idx[t] = sidx[t];
    __syncthreads();
    // fallback: fewer than K candidates -> top_k picks the -1 fillers at lowest indices
    if (t == 0 && valid < K) {
        int fill = valid;
        for (int flat = 0; fill < K && flat < HW; ++flat) {
            int gi = b * HW + flat;
            bool cand = (mask[gi] > 0.f) && (scores[gi] > 0.f);
            if (!cand) final_idx[fill++] = flat;
        }
    }
    __syncthreads();

    int flat = final_idx[t];
    int u = flat >> 9, v = flat & (W - 1);
    float p0 = bev[((b * 7 + 3) << 18) + flat];
    float p1 = bev[((b * 7 + 4) << 18) + flat];
    int kb = b * K + t;
    out_kpts[kb * 4 + 0] = p0;
    out_kpts[kb * 4 + 1] = p1;
    out_kpts[kb * 4 + 2] = 0.f;
    out_kpts[kb * 4 + 3] = 1.f;
    out_pix[kb * 2 + 0] = (float)u;
    out_pix[kb * 2 + 1] = (float)v;
    topk_idx[kb] = flat;
}

// ---------------- feature gather: feas[b,c,k] = feat[b,c,u,v] ----------------
__global__ __launch_bounds__(512) void gather_k(const float* __restrict__ feat,
                                                const int* __restrict__ topk_idx,
                                                float* __restrict__ out) {
    int c = blockIdx.x, b = blockIdx.y, k = threadIdx.x;
    int flat = topk_idx[b * K + k];
    out[(b * CFEAT + c) * K + k] = feat[((b * CFEAT + c) << 18) + flat];
}

extern "C" void kernel_launch(void* const* d_in, const int* in_sizes, int n_in,
                              void* d_out, int out_size, void* d_ws, size_t ws_size,
                              hipStream_t stream) {
    const float* bev  = (const float*)d_in[0];
    const float* raw  = (const float*)d_in[1];
    const float* feat = (const float*)d_in[2];
    // d_in[3] = num_kpt (512) — compile-time K here.

    float* out = (float*)d_out;
    float* out_scores = out;                                       // b*h*w
    float* out_kpts   = out + NTOT;                                // b*K*4
    float* out_feas   = out + NTOT + B * K * 4;                    // b*CFEAT*K
    float* out_pix    = out + NTOT + B * K * 4 + B * CFEAT * K;    // b*K*2

    char* w = (char*)d_ws;
    float*    tmp   = (float*)(w);
    float*    mask  = (float*)(w + 4u * 1024 * 1024);
    float*    supp  = (float*)(w + 8u * 1024 * 1024);
    unsigned* hist  = (unsigned*)(w + 12u * 1024 * 1024);          // B*NBINS u32 = 1 MB
    int*      count = (int*)(w + 13u * 1024 * 1024);               // B ints
    float*    cval  = (float*)(w + 13u * 1024 * 1024 + 256);       // B*CAP f32
    int*      cidx  = (int*)(w + 13u * 1024 * 1024 + 256 + B * CAP * 4);
    int*      topk  = (int*)(w + 13u * 1024 * 1024 + 256 + 2u * B * CAP * 4);

    const int TB = 256;
    const int GN = (NTOT + TB - 1) / TB;

    zero_ws_k<<<(B * NBINS + TB - 1) / TB, TB, 0, stream>>>(hist, count);
    score_k<<<GN, TB, 0, stream>>>(bev, raw, out_scores);

    // max_mask = scores == maxpool(scores)
    hmax_k<<<GN, TB, 0, stream>>>(out_scores, tmp);
    vmax_eq_k<<<GN, TB, 0, stream>>>(tmp, out_scores, mask);

    for (int it = 0; it < 2; ++it) {
        // supp = maxpool(mask) > 0
        hmax_k<<<GN, TB, 0, stream>>>(mask, tmp);
        vmax_supp_k<<<GN, TB, 0, stream>>>(tmp, supp);
        // new_max = (supp_scores == maxpool(supp_scores)) & ~supp ; mask |= new_max
        hmax_supp_k<<<GN, TB, 0, stream>>>(out_scores, supp, tmp);
        vmax_new_k<<<GN, TB, 0, stream>>>(tmp, out_scores, supp, mask);
    }

    compact_k<<<GN, TB, 0, stream>>>(out_scores, mask, cval, cidx, count, hist);
    select_k<<<B, 512, 0, stream>>>(cval, cidx, count, hist, out_scores, mask, bev,
                                    out_kpts, out_pix, topk);
    gather_k<<<dim3(CFEAT, B), 512, 0, stream>>>(feat, topk, out_feas);
}

// Round 2
// 738.666 us; speedup vs baseline: 1.5724x; 1.5724x over previous
//
#include <hip/hip_runtime.h>
#include <cfloat>

#define W 512
#define H 512
#define B 4
#define HW (W*H)
#define NTOT (B*HW)
#define CFEAT 128
#define K 512
#define NBINS 65536
#define CAP 49152   // >= theoretical max NMS maxima per batch
#define CNT_STRIDE 16  // pad batch counters to separate 64B cache lines

// ---------------- init ----------------
__global__ void zero_ws_k(unsigned* __restrict__ hist, int* __restrict__ count) {
    int i = blockIdx.x * blockDim.x + threadIdx.x;
    if (i < B * NBINS) hist[i] = 0u;
    if (i < B) count[i * CNT_STRIDE] = 0;
}

// ---------------- score2d = raw * (bev[:,2] > 0) ----------------
__global__ void score_k(const float* __restrict__ bev, const float* __restrict__ raw,
                        float* __restrict__ scores) {
    int i = blockIdx.x * blockDim.x + threadIdx.x;
    if (i >= NTOT) return;
    int b = i >> 18;
    int hw = i & (HW - 1);
    float g = bev[(b * 7 + 2) * HW + hw] > 0.f ? 1.f : 0.f;
    scores[i] = raw[i] * g;
}

// ---------------- horizontal 7-tap max ----------------
__global__ void hmax_k(const float* __restrict__ in, float* __restrict__ out) {
    int i = blockIdx.x * blockDim.x + threadIdx.x;
    if (i >= NTOT) return;
    int v = i & (W - 1);
    float m = in[i];
#pragma unroll
    for (int d = 1; d <= 3; ++d) {
        if (v - d >= 0) m = fmaxf(m, in[i - d]);
        if (v + d < W)  m = fmaxf(m, in[i + d]);
    }
    out[i] = m;
}

// horizontal 7-tap max of suppressed scores (supp ? 0 : scores), on the fly
__global__ void hmax_supp_k(const float* __restrict__ scores, const float* __restrict__ supp,
                            float* __restrict__ out) {
    int i = blockIdx.x * blockDim.x + threadIdx.x;
    if (i >= NTOT) return;
    int v = i & (W - 1);
    float m = supp[i] > 0.f ? 0.f : scores[i];
#pragma unroll
    for (int d = 1; d <= 3; ++d) {
        if (v - d >= 0) { int j = i - d; m = fmaxf(m, supp[j] > 0.f ? 0.f : scores[j]); }
        if (v + d < W)  { int j = i + d; m = fmaxf(m, supp[j] > 0.f ? 0.f : scores[j]); }
    }
    out[i] = m;
}

// ---------------- vertical 7-tap max, fused consumers ----------------
__global__ void vmax_eq_k(const float* __restrict__ tmp, const float* __restrict__ scores,
                          float* __restrict__ mask) {
    int i = blockIdx.x * blockDim.x + threadIdx.x;
    if (i >= NTOT) return;
    int h = (i >> 9) & (H - 1);
    float m = tmp[i];
#pragma unroll
    for (int d = 1; d <= 3; ++d) {
        if (h - d >= 0) m = fmaxf(m, tmp[i - (d << 9)]);
        if (h + d < H)  m = fmaxf(m, tmp[i + (d << 9)]);
    }
    mask[i] = (scores[i] == m) ? 1.f : 0.f;
}

__global__ void vmax_supp_k(const float* __restrict__ tmp, float* __restrict__ supp) {
    int i = blockIdx.x * blockDim.x + threadIdx.x;
    if (i >= NTOT) return;
    int h = (i >> 9) & (H - 1);
    float m = tmp[i];
#pragma unroll
    for (int d = 1; d <= 3; ++d) {
        if (h - d >= 0) m = fmaxf(m, tmp[i - (d << 9)]);
        if (h + d < H)  m = fmaxf(m, tmp[i + (d << 9)]);
    }
    supp[i] = m > 0.f ? 1.f : 0.f;
}

// middle iteration: new_max = (supp_scores == vmax(tmp)) & !supp ; mask |= new_max
__global__ void vmax_new_k(const float* __restrict__ tmp, const float* __restrict__ scores,
                           const float* __restrict__ supp, float* __restrict__ mask) {
    int i = blockIdx.x * blockDim.x + threadIdx.x;
    if (i >= NTOT) return;
    int h = (i >> 9) & (H - 1);
    float m = tmp[i];
#pragma unroll
    for (int d = 1; d <= 3; ++d) {
        if (h - d >= 0) m = fmaxf(m, tmp[i - (d << 9)]);
        if (h + d < H)  m = fmaxf(m, tmp[i + (d << 9)]);
    }
    float sup = supp[i];
    float ss = sup > 0.f ? 0.f : scores[i];
    bool newm = (ss == m) && (sup == 0.f);
    mask[i] = ((mask[i] > 0.f) || newm) ? 1.f : 0.f;
}

// final iteration fused with compaction + histogram.
// Block-aggregated count atomic: one global atomicAdd per block per batch
// (count padded to distinct cache lines) instead of 20k same-line atomics.
__global__ void vmax_new_compact_k(const float* __restrict__ tmp, const float* __restrict__ scores,
                                   const float* __restrict__ supp, float* __restrict__ mask,
                                   float* __restrict__ cval, int* __restrict__ cidx,
                                   int* __restrict__ count, unsigned* __restrict__ hist) {
    __shared__ int lcount, lbase;
    int i = blockIdx.x * blockDim.x + threadIdx.x;
    int h = (i >> 9) & (H - 1);
    float m = tmp[i];
#pragma unroll
    for (int d = 1; d <= 3; ++d) {
        if (h - d >= 0) m = fmaxf(m, tmp[i - (d << 9)]);
        if (h + d < H)  m = fmaxf(m, tmp[i + (d << 9)]);
    }
    float sup = supp[i];
    float v = scores[i];
    float ss = sup > 0.f ? 0.f : v;
    bool newm = (ss == m) && (sup == 0.f);
    bool mk = (mask[i] > 0.f) || newm;
    mask[i] = mk ? 1.f : 0.f;
    bool cand = mk && (v > 0.f);

    if (threadIdx.x == 0) lcount = 0;
    __syncthreads();
    int p_loc = 0;
    if (cand) p_loc = atomicAdd(&lcount, 1);
    __syncthreads();
    int b = i >> 18;  // block spans 256 consecutive i -> single batch
    if (threadIdx.x == 0)
        lbase = lcount ? atomicAdd(&count[b * CNT_STRIDE], lcount) : 0;
    __syncthreads();
    if (cand) {
        int p = lbase + p_loc;
        if (p < CAP) { cval[b * CAP + p] = v; cidx[b * CAP + p] = i & (HW - 1); }
        unsigned bin = (unsigned)(v * 65536.f);
        if (bin > 65535u) bin = 65535u;
        atomicAdd(&hist[b * NBINS + bin], 1u);
    }
}

// ---------------- per-batch exact top-K (value desc, idx asc) ----------------
__global__ __launch_bounds__(512) void select_k(
    const float* __restrict__ cval, const int* __restrict__ cidx,
    const int* __restrict__ count, const unsigned* __restrict__ hist,
    const float* __restrict__ scores, const float* __restrict__ mask,
    const float* __restrict__ bev,
    float* __restrict__ out_kpts, float* __restrict__ out_pix, int* __restrict__ topk_idx) {
    __shared__ float sval[1024];
    __shared__ int   sidx[1024];
    __shared__ unsigned part[512];
    __shared__ int final_idx[K];
    __shared__ int nsel_s, tbin_s;

    int b = blockIdx.x, t = threadIdx.x;
    int total = count[b * CNT_STRIDE];
    if (total > CAP) total = CAP;
    const unsigned* Hh = hist + b * NBINS;

    unsigned s = 0;
    const int SPAN = NBINS / 512;
#pragma unroll 4
    for (int i = 0; i < SPAN; ++i) s += Hh[t * SPAN + i];
    part[t] = s;
    if (t == 0) nsel_s = 0;
    __syncthreads();

    if (t == 0) {
        if (total <= K) {
            tbin_s = 0;
        } else {
            unsigned acc = 0; int seg = 0; unsigned before = 0;
            for (int sg = 511; sg >= 0; --sg) {
                if (acc + part[sg] >= (unsigned)K) { seg = sg; before = acc; break; }
                acc += part[sg];
            }
            int base = seg * SPAN;
            unsigned a2 = before; int T = base;
            for (int bin = base + SPAN - 1; bin >= base; --bin) {
                a2 += Hh[bin];
                if (a2 >= (unsigned)K) { T = bin; break; }
            }
            tbin_s = T;
        }
    }
    __syncthreads();
    int tb = tbin_s;

    for (int i = t; i < total; i += 512) {
        float v = cval[b * CAP + i];
        unsigned bin = (unsigned)(v * 65536.f);
        if (bin > 65535u) bin = 65535u;
        if ((int)bin >= tb) {
            int p = atomicAdd(&nsel_s, 1);
            if (p < 1024) { sval[p] = v; sidx[p] = cidx[b * CAP + i]; }
        }
    }
    __syncthreads();
    int ns = nsel_s < 1024 ? nsel_s : 1024;
    for (int i = t; i < 1024; i += 512)
        if (i >= ns) { sval[i] = -FLT_MAX; sidx[i] = 0x40000000 + i; }
    __syncthreads();

    // bitonic sort: value desc, ties idx asc
    for (int kk = 2; kk <= 1024; kk <<= 1) {
        for (int j = kk >> 1; j > 0; j >>= 1) {
            for (int idx = t; idx < 1024; idx += 512) {
                int p = idx ^ j;
                if (p > idx) {
                    float va = sval[idx], vb = sval[p];
                    int ia = sidx[idx], ib = sidx[p];
                    bool up = ((idx & kk) == 0);
                    bool b_first = (vb > va) || (vb == va && ib < ia);
                    if (b_first == up) {
                        sval[idx] = vb; sval[p] = va;
                        sidx[idx] = ib; sidx[p] = ia;
                    }
                }
            }
            __syncthreads();
        }
    }

    int valid = total < K ? total : K;
    if (t < valid) final_idx[t] = sidx[t];
    __syncthreads();
    if (t == 0 && valid < K) {
        int fill = valid;
        for (int flat = 0; fill < K && flat < HW; ++flat) {
            int gi = b * HW + flat;
            bool cand = (mask[gi] > 0.f) && (scores[gi] > 0.f);
            if (!cand) final_idx[fill++] = flat;
        }
    }
    __syncthreads();

    int flat = final_idx[t];
    int u = flat >> 9, v = flat & (W - 1);
    float p0 = bev[((b * 7 + 3) << 18) + flat];
    float p1 = bev[((b * 7 + 4) << 18) + flat];
    int kb = b * K + t;
    out_kpts[kb * 4 + 0] = p0;
    out_kpts[kb * 4 + 1] = p1;
    out_kpts[kb * 4 + 2] = 0.f;
    out_kpts[kb * 4 + 3] = 1.f;
    out_pix[kb * 2 + 0] = (float)u;
    out_pix[kb * 2 + 1] = (float)v;
    topk_idx[kb] = flat;
}

// ---------------- feature gather ----------------
__global__ __launch_bounds__(512) void gather_k(const float* __restrict__ feat,
                                                const int* __restrict__ topk_idx,
                                                float* __restrict__ out) {
    int c = blockIdx.x, b = blockIdx.y, k = threadIdx.x;
    int flat = topk_idx[b * K + k];
    out[(b * CFEAT + c) * K + k] = feat[((b * CFEAT + c) << 18) + flat];
}

extern "C" void kernel_launch(void* const* d_in, const int* in_sizes, int n_in,
                              void* d_out, int out_size, void* d_ws, size_t ws_size,
                              hipStream_t stream) {
    const float* bev  = (const float*)d_in[0];
    const float* raw  = (const float*)d_in[1];
    const float* feat = (const float*)d_in[2];

    float* out = (float*)d_out;
    float* out_scores = out;
    float* out_kpts   = out + NTOT;
    float* out_feas   = out + NTOT + B * K * 4;
    float* out_pix    = out + NTOT + B * K * 4 + B * CFEAT * K;

    char* w = (char*)d_ws;
    float*    tmp   = (float*)(w);
    float*    mask  = (float*)(w + 4u * 1024 * 1024);
    float*    supp  = (float*)(w + 8u * 1024 * 1024);
    unsigned* hist  = (unsigned*)(w + 12u * 1024 * 1024);
    int*      count = (int*)(w + 13u * 1024 * 1024);
    float*    cval  = (float*)(w + 13u * 1024 * 1024 + 256);
    int*      cidx  = (int*)(w + 13u * 1024 * 1024 + 256 + B * CAP * 4);
    int*      topk  = (int*)(w + 13u * 1024 * 1024 + 256 + 2u * B * CAP * 4);

    const int TB = 256;
    const int GN = (NTOT + TB - 1) / TB;

    zero_ws_k<<<(B * NBINS + TB - 1) / TB, TB, 0, stream>>>(hist, count);
    score_k<<<GN, TB, 0, stream>>>(bev, raw, out_scores);

    // max_mask = scores == maxpool(scores)
    hmax_k<<<GN, TB, 0, stream>>>(out_scores, tmp);
    vmax_eq_k<<<GN, TB, 0, stream>>>(tmp, out_scores, mask);

    // iteration 0
    hmax_k<<<GN, TB, 0, stream>>>(mask, tmp);
    vmax_supp_k<<<GN, TB, 0, stream>>>(tmp, supp);
    hmax_supp_k<<<GN, TB, 0, stream>>>(out_scores, supp, tmp);
    vmax_new_k<<<GN, TB, 0, stream>>>(tmp, out_scores, supp, mask);

    // iteration 1 (final) — fused with compact+hist
    hmax_k<<<GN, TB, 0, stream>>>(mask, tmp);
    vmax_supp_k<<<GN, TB, 0, stream>>>(tmp, supp);
    hmax_supp_k<<<GN, TB, 0, stream>>>(out_scores, supp, tmp);
    vmax_new_compact_k<<<GN, TB, 0, stream>>>(tmp, out_scores, supp, mask,
                                              cval, cidx, count, hist);

    select_k<<<B, 512, 0, stream>>>(cval, cidx, count, hist, out_scores, mask, bev,
                                    out_kpts, out_pix, topk);
    gather_k<<<dim3(CFEAT, B), 512, 0, stream>>>(feat, topk, out_feas);
}

// Round 3
// 693.278 us; speedup vs baseline: 1.6753x; 1.0655x over previous
//
#include <hip/hip_runtime.h>
#include <cfloat>

#define W 512
#define H 512
#define B 4
#define HW (W*H)
#define NTOT (B*HW)
#define CFEAT 128
#define K 512
#define NBINS 65536
#define CAP 49152
#define CNT_STRIDE 16

// ---------------- init ----------------
__global__ void zero_ws_k(unsigned* __restrict__ hist, int* __restrict__ count) {
    int i = blockIdx.x * blockDim.x + threadIdx.x;
    if (i < B * NBINS) hist[i] = 0u;
    if (i < B) count[i * CNT_STRIDE] = 0;
}

// ---------------- fully fused NMS: score + 5 pools + mask + compact + hist ----
// Tile 32x32 output, halo 15 -> 62x62 staged scores. All pool stages in LDS.
// Stage regions (62-grid coords):  A: mask_init on [3,58]^2
//   B1: supp0 on [6,55]^2   B2: mask|=new0 on [9,52]^2
//   C1: supp1 on [12,49]^2  C2: final mask on [15,46]^2 (= the 32x32 center)
__global__ __launch_bounds__(256) void nms_fused_k(
    const float* __restrict__ bev, const float* __restrict__ raw,
    float* __restrict__ out_scores, float* __restrict__ mask_g,
    float* __restrict__ cval, int* __restrict__ cidx,
    int* __restrict__ count, unsigned* __restrict__ hist) {
    __shared__ float SS[62 * 62];   // scores (persistent)
    __shared__ float ST[62 * 62];   // separable-pool temp (reused 5x)
    __shared__ float SM[56 * 56];   // mask, offset 3
    __shared__ float SP[50 * 50];   // supp0 (offset 6), then supp1 (offset 12, 38x38)
    __shared__ int lcount, lbase;

    const int b = blockIdx.z;
    const int gx0 = blockIdx.x * 32 - 15;
    const int gy0 = blockIdx.y * 32 - 15;
    const int t = threadIdx.x;
    const float* raw_b = raw + b * HW;
    const float* gdr_b = bev + (b * 7 + 2) * HW;

    // load 62x62 scores = raw * (guider > 0), 0 outside image
    for (int idx = t; idx < 62 * 62; idx += 256) {
        int y = idx / 62, x = idx - y * 62;
        int gx = gx0 + x, gy = gy0 + y;
        float v = 0.f;
        if ((unsigned)gx < (unsigned)W && (unsigned)gy < (unsigned)H) {
            int g = (gy << 9) + gx;
            v = gdr_b[g] > 0.f ? raw_b[g] : 0.f;
        }
        SS[idx] = v;
    }
    __syncthreads();

#define HMAX7(PTR, STRIDE) ({ const float* _r = (PTR); \
    float _m = fmaxf(fmaxf(fmaxf(_r[-3*(STRIDE)], _r[-2*(STRIDE)]), fmaxf(_r[-(STRIDE)], _r[0])), \
                     fmaxf(fmaxf(_r[(STRIDE)], _r[2*(STRIDE)]), _r[3*(STRIDE)])); _m; })

    // ---- Stage A ---- h: rows [0,61] x cols [3,58]
    for (int idx = t; idx < 62 * 56; idx += 256) {
        int y = idx / 56, x = 3 + (idx - (idx / 56) * 56);
        ST[y * 62 + x] = HMAX7(SS + y * 62 + x, 1);
    }
    __syncthreads();
    // v + eq: [3,58]^2 -> SM
    for (int idx = t; idx < 56 * 56; idx += 256) {
        int y = 3 + idx / 56, x = 3 + (idx % 56);
        float m = HMAX7(ST + y * 62 + x, 62);
        int gx = gx0 + x, gy = gy0 + y;
        bool inb = (unsigned)gx < (unsigned)W && (unsigned)gy < (unsigned)H;
        SM[(y - 3) * 56 + (x - 3)] = (inb && SS[y * 62 + x] == m) ? 1.f : 0.f;
    }
    __syncthreads();

    // ---- Stage B1: supp0 ---- h: rows [3,58] x cols [6,55]
    for (int idx = t; idx < 56 * 50; idx += 256) {
        int y = 3 + idx / 50, x = 6 + (idx % 50);
        ST[y * 62 + x] = HMAX7(SM + (y - 3) * 56 + (x - 3), 1);
    }
    __syncthreads();
    for (int idx = t; idx < 50 * 50; idx += 256) {
        int y = 6 + idx / 50, x = 6 + (idx % 50);
        float m = HMAX7(ST + y * 62 + x, 62);
        SP[(y - 6) * 50 + (x - 6)] = m > 0.f ? 1.f : 0.f;
    }
    __syncthreads();

    // ---- Stage B2: mask |= new0 ---- h: rows [6,55] x cols [9,52], src = supp0?0:scores
    for (int idx = t; idx < 50 * 44; idx += 256) {
        int y = 6 + idx / 44, x = 9 + (idx % 44);
        float m = -FLT_MAX;
#pragma unroll
        for (int dx = -3; dx <= 3; ++dx) {
            int xx = x + dx;
            float s = SP[(y - 6) * 50 + (xx - 6)] > 0.f ? 0.f : SS[y * 62 + xx];
            m = fmaxf(m, s);
        }
        ST[y * 62 + x] = m;
    }
    __syncthreads();
    for (int idx = t; idx < 44 * 44; idx += 256) {
        int y = 9 + idx / 44, x = 9 + (idx % 44);
        float m = HMAX7(ST + y * 62 + x, 62);
        float sup = SP[(y - 6) * 50 + (x - 6)];
        float ss = sup > 0.f ? 0.f : SS[y * 62 + x];
        bool nm = (ss == m) && (sup == 0.f);
        int gx = gx0 + x, gy = gy0 + y;
        bool inb = (unsigned)gx < (unsigned)W && (unsigned)gy < (unsigned)H;
        int mi = (y - 3) * 56 + (x - 3);
        SM[mi] = (SM[mi] > 0.f || (nm && inb)) ? 1.f : 0.f;
    }
    __syncthreads();

    // ---- Stage C1: supp1 (stored in SP at offset 12, pitch 38) ----
    for (int idx = t; idx < 44 * 38; idx += 256) {
        int y = 9 + idx / 38, x = 12 + (idx % 38);
        ST[y * 62 + x] = HMAX7(SM + (y - 3) * 56 + (x - 3), 1);
    }
    __syncthreads();
    for (int idx = t; idx < 38 * 38; idx += 256) {
        int y = 12 + idx / 38, x = 12 + (idx % 38);
        float m = HMAX7(ST + y * 62 + x, 62);
        SP[(y - 12) * 38 + (x - 12)] = m > 0.f ? 1.f : 0.f;  // supp0 dead, reuse
    }
    __syncthreads();

    // ---- Stage C2: final ---- h: rows [12,49] x cols [15,46], src = supp1?0:scores
    for (int idx = t; idx < 38 * 32; idx += 256) {
        int y = 12 + idx / 32, x = 15 + (idx % 32);
        float m = -FLT_MAX;
#pragma unroll
        for (int dx = -3; dx <= 3; ++dx) {
            int xx = x + dx;
            float s = SP[(y - 12) * 38 + (xx - 12)] > 0.f ? 0.f : SS[y * 62 + xx];
            m = fmaxf(m, s);
        }
        ST[y * 62 + x] = m;
    }
    __syncthreads();

    // v + epilogue over the 32x32 center (4 px/thread)
    float vloc[4]; int gloc[4]; int nloc = 0;
#pragma unroll
    for (int q = 0; q < 4; ++q) {
        int idx = t + q * 256;
        int y = 15 + idx / 32, x = 15 + (idx % 32);
        float m = HMAX7(ST + y * 62 + x, 62);
        float sup = SP[(y - 12) * 38 + (x - 12)];
        float v = SS[y * 62 + x];
        float ss = sup > 0.f ? 0.f : v;
        bool nm = (ss == m) && (sup == 0.f);
        bool mk = (SM[(y - 3) * 56 + (x - 3)] > 0.f) || nm;
        int gx = gx0 + x, gy = gy0 + y;
        int g = (gy << 9) + gx;
        out_scores[b * HW + g] = v;
        mask_g[b * HW + g] = mk ? 1.f : 0.f;
        if (mk && v > 0.f) { vloc[nloc] = v; gloc[nloc] = g; ++nloc; }
    }
    if (t == 0) lcount = 0;
    __syncthreads();
    int p0 = nloc ? atomicAdd(&lcount, nloc) : 0;
    __syncthreads();
    if (t == 0) lbase = lcount ? atomicAdd(&count[b * CNT_STRIDE], lcount) : 0;
    __syncthreads();
    for (int j = 0; j < nloc; ++j) {
        int p = lbase + p0 + j;
        float v = vloc[j];
        if (p < CAP) { cval[b * CAP + p] = v; cidx[b * CAP + p] = gloc[j]; }
        unsigned bin = (unsigned)(v * 65536.f);
        if (bin > 65535u) bin = 65535u;
        atomicAdd(&hist[b * NBINS + bin], 1u);
    }
#undef HMAX7
}

// ---------------- per-batch exact top-K (value desc, idx asc) ----------------
__global__ __launch_bounds__(512) void select_k(
    const float* __restrict__ cval, const int* __restrict__ cidx,
    const int* __restrict__ count, const unsigned* __restrict__ hist,
    const float* __restrict__ scores, const float* __restrict__ mask,
    const float* __restrict__ bev,
    float* __restrict__ out_kpts, float* __restrict__ out_pix, int* __restrict__ topk_idx) {
    __shared__ float sval[1024];
    __shared__ int   sidx[1024];
    __shared__ unsigned part[512];
    __shared__ int final_idx[K];
    __shared__ int nsel_s, tbin_s;

    int b = blockIdx.x, t = threadIdx.x;
    int total = count[b * CNT_STRIDE];
    if (total > CAP) total = CAP;
    const unsigned* Hh = hist + b * NBINS;

    unsigned s = 0;
    const int SPAN = NBINS / 512;
#pragma unroll 4
    for (int i = 0; i < SPAN; ++i) s += Hh[t * SPAN + i];
    part[t] = s;
    if (t == 0) nsel_s = 0;
    __syncthreads();

    if (t == 0) {
        if (total <= K) {
            tbin_s = 0;
        } else {
            unsigned acc = 0; int seg = 0; unsigned before = 0;
            for (int sg = 511; sg >= 0; --sg) {
                if (acc + part[sg] >= (unsigned)K) { seg = sg; before = acc; break; }
                acc += part[sg];
            }
            int base = seg * SPAN;
            unsigned a2 = before; int T = base;
            for (int bin = base + SPAN - 1; bin >= base; --bin) {
                a2 += Hh[bin];
                if (a2 >= (unsigned)K) { T = bin; break; }
            }
            tbin_s = T;
        }
    }
    __syncthreads();
    int tb = tbin_s;

    for (int i = t; i < total; i += 512) {
        float v = cval[b * CAP + i];
        unsigned bin = (unsigned)(v * 65536.f);
        if (bin > 65535u) bin = 65535u;
        if ((int)bin >= tb) {
            int p = atomicAdd(&nsel_s, 1);
            if (p < 1024) { sval[p] = v; sidx[p] = cidx[b * CAP + i]; }
        }
    }
    __syncthreads();
    int ns = nsel_s < 1024 ? nsel_s : 1024;
    for (int i = t; i < 1024; i += 512)
        if (i >= ns) { sval[i] = -FLT_MAX; sidx[i] = 0x40000000 + i; }
    __syncthreads();

    for (int kk = 2; kk <= 1024; kk <<= 1) {
        for (int j = kk >> 1; j > 0; j >>= 1) {
            for (int idx = t; idx < 1024; idx += 512) {
                int p = idx ^ j;
                if (p > idx) {
                    float va = sval[idx], vb = sval[p];
                    int ia = sidx[idx], ib = sidx[p];
                    bool up = ((idx & kk) == 0);
                    bool b_first = (vb > va) || (vb == va && ib < ia);
                    if (b_first == up) {
                        sval[idx] = vb; sval[p] = va;
                        sidx[idx] = ib; sidx[p] = ia;
                    }
                }
            }
            __syncthreads();
        }
    }

    int valid = total < K ? total : K;
    if (t < valid) final_idx[t] = sidx[t];
    __syncthreads();
    if (t == 0 && valid < K) {
        int fill = valid;
        for (int flat = 0; fill < K && flat < HW; ++flat) {
            int gi = b * HW + flat;
            bool cand = (mask[gi] > 0.f) && (scores[gi] > 0.f);
            if (!cand) final_idx[fill++] = flat;
        }
    }
    __syncthreads();

    int flat = final_idx[t];
    int u = flat >> 9, v = flat & (W - 1);
    float p0 = bev[((b * 7 + 3) << 18) + flat];
    float p1 = bev[((b * 7 + 4) << 18) + flat];
    int kb = b * K + t;
    out_kpts[kb * 4 + 0] = p0;
    out_kpts[kb * 4 + 1] = p1;
    out_kpts[kb * 4 + 2] = 0.f;
    out_kpts[kb * 4 + 3] = 1.f;
    out_pix[kb * 2 + 0] = (float)u;
    out_pix[kb * 2 + 1] = (float)v;
    topk_idx[kb] = flat;
}

// ---------------- feature gather ----------------
__global__ __launch_bounds__(512) void gather_k(const float* __restrict__ feat,
                                                const int* __restrict__ topk_idx,
                                                float* __restrict__ out) {
    int c = blockIdx.x, b = blockIdx.y, k = threadIdx.x;
    int flat = topk_idx[b * K + k];
    out[(b * CFEAT + c) * K + k] = feat[((b * CFEAT + c) << 18) + flat];
}

extern "C" void kernel_launch(void* const* d_in, const int* in_sizes, int n_in,
                              void* d_out, int out_size, void* d_ws, size_t ws_size,
                              hipStream_t stream) {
    const float* bev  = (const float*)d_in[0];
    const float* raw  = (const float*)d_in[1];
    const float* feat = (const float*)d_in[2];

    float* out = (float*)d_out;
    float* out_scores = out;
    float* out_kpts   = out + NTOT;
    float* out_feas   = out + NTOT + B * K * 4;
    float* out_pix    = out + NTOT + B * K * 4 + B * CFEAT * K;

    char* w = (char*)d_ws;
    float*    mask  = (float*)(w);                                  // 4 MB
    unsigned* hist  = (unsigned*)(w + 4u * 1024 * 1024);            // 1 MB
    int*      count = (int*)(w + 5u * 1024 * 1024);                 // 256 B
    float*    cval  = (float*)(w + 5u * 1024 * 1024 + 256);
    int*      cidx  = (int*)(w + 5u * 1024 * 1024 + 256 + B * CAP * 4);
    int*      topk  = (int*)(w + 5u * 1024 * 1024 + 256 + 2u * B * CAP * 4);

    zero_ws_k<<<(B * NBINS + 255) / 256, 256, 0, stream>>>(hist, count);
    nms_fused_k<<<dim3(W / 32, H / 32, B), 256, 0, stream>>>(
        bev, raw, out_scores, mask, cval, cidx, count, hist);
    select_k<<<B, 512, 0, stream>>>(cval, cidx, count, hist, out_scores, mask, bev,
                                    out_kpts, out_pix, topk);
    gather_k<<<dim3(CFEAT, B), 512, 0, stream>>>(feat, topk, out_feas);
}